// Round 6
// baseline (622.259 us; speedup 1.0000x reference)
//
#include <hip/hip_runtime.h>
#include <cstdint>
#include <cstddef>

// LatentNeuralSDE: 100 sequential EM steps, B=32768, LAT=10.
// R9: R8 structure, tanh via Pade[5/4] rational (zero transcendentals):
// tanh(x) ~= x(945+105u+u^2)/(945+420u+15u^2), u=x^2, clamped to [-1,1]
// (CF-of-tanh truncation; max err ~1.1e-3, sub-ulp at bf16 output).
// Pairs evaluated as f32x2 packed math (v_pk_fma_f32) with ONE shared
// rcp per pair (r=rcp(q0*q1); 1/q0=q1*r). SC-folding removed (rational
// wants raw preacts); softplus gets log2e folded into G1/gb1; EM update
// vectorized. W1 + W2 t2=4..7 in frag-linear LDS behind anti-LICM
// clobber; W2 t2=0..3 / W3 / G1 / G2 persistent in registers.

#define B_TOT 32768
#define NSTEP 100
#define MT    64

typedef __attribute__((ext_vector_type(8))) short sh8;
typedef __attribute__((ext_vector_type(4))) float f32x4;
typedef __attribute__((ext_vector_type(2))) float f32x2;
typedef __attribute__((ext_vector_type(4))) unsigned int u32x4;

#define MFMA(a, b, c) __builtin_amdgcn_mfma_f32_16x16x32_bf16((a), (b), (c), 0, 0, 0)

#define L2E 1.4426950408889634f   // log2(e)
#define LN2 0.6931471805599453f

// fragment table layout in LDS
#define W1F 0            // 8 frags  (L1 z-part, t=0..7)
#define W2F 8            // 16 frags (t2=4..7): W2F + (t2-4)*4 + kt
#define NFR 24

struct __align__(16) Lds {
  union {
    float ar[MT][100];               // encoder outputs (prologue only)
    struct {
      short wfr[NFR][64][8];         // frag-linear weight frags (conflict-free)
    } s;
  } u;                               // 25600 B
  float tsl[104];
};

static __device__ __forceinline__ short f2bf(float v) {  // RTNE (weights, one-time)
  unsigned u = __builtin_bit_cast(unsigned, v);
  u += 0x7fffu + ((u >> 16) & 1u);
  return (short)(u >> 16);
}
// 2 f32 -> packed 2x bf16 (RTNE), one HW instruction (no builtin on gfx950)
static __device__ __forceinline__ unsigned cvtpk(float lo, float hi) {
  unsigned r;
  asm("v_cvt_pk_bf16_f32 %0, %1, %2" : "=v"(r) : "v"(lo), "v"(hi));
  return r;
}
static __device__ __forceinline__ sh8 mk4(unsigned a, unsigned b, unsigned c, unsigned d) {
  return __builtin_bit_cast(sh8, (u32x4){a, b, c, d});
}
// pair tanh: Pade[5/4] + shared rcp, packed f32x2 math, -> packed bf16x2
static __device__ __forceinline__ unsigned tanh2pk(float x0, float x1) {
  const f32x2 c945 = {945.0f, 945.0f};
  const f32x2 c420 = {420.0f, 420.0f};
  const f32x2 c15  = {15.0f, 15.0f};
  f32x2 x = {x0, x1};
  f32x2 u = x * x;
  f32x2 num = x * __builtin_elementwise_fma(u + 105.0f, u, c945);
  f32x2 den = __builtin_elementwise_fma(
      __builtin_elementwise_fma(u, c15, c420), u, c945);
  float r  = __builtin_amdgcn_rcpf(den[0] * den[1]);
  float t0 = num[0] * (den[1] * r);
  float t1 = num[1] * (den[0] * r);
  t0 = fmaxf(fminf(t0, 1.0f), -1.0f);
  t1 = fmaxf(fminf(t1, 1.0f), -1.0f);
  return cvtpk(t0, t1);
}
// softplus with log2e pre-folded into the matmul: y = L2E*(Wx+b)
static __device__ __forceinline__ float softplus_post(float y) {
  float e = __builtin_amdgcn_exp2f(y);
  float l = __builtin_amdgcn_logf(e + 1.0f);       // log2
  float s = (y > 28.8539008177792681f) ? y : l;    // x>20 guard
  return s * LN2;
}

__global__ __launch_bounds__(256, 2)
void sde_kernel(const float* __restrict__ z0, const float* __restrict__ activity,
                const float* __restrict__ rest, const float* __restrict__ ts,
                const float* __restrict__ noise,
                const float* __restrict__ aW1, const float* __restrict__ ab1,
                const float* __restrict__ aW2, const float* __restrict__ ab2,
                const float* __restrict__ rW1, const float* __restrict__ rb1,
                const float* __restrict__ rW2, const float* __restrict__ rb2,
                const float* __restrict__ dW1, const float* __restrict__ db1,
                const float* __restrict__ dW2, const float* __restrict__ db2,
                const float* __restrict__ dW3, const float* __restrict__ db3,
                const float* __restrict__ gW1, const float* __restrict__ gb1,
                const float* __restrict__ gW2, const float* __restrict__ gb2,
                float* __restrict__ out)
{
  __shared__ Lds lds;
  const int tid  = threadIdx.x;
  const int lane = tid & 63;
  const int wave = tid >> 6;
  const int n    = lane & 15;   // batch col (B/D col) / A-row m in weight gathers
  const int quad = lane >> 4;
  const int slab = wave * 16;
  const int mblk = blockIdx.x * MT;
  const int rowg = mblk + slab + n;   // this lane's global batch row

  if (tid < 101) lds.tsl[tid] = ts[tid];
  float tcur = ts[0];

  // ---------------- encoders -> ar (wave-private rows) ----------------
  {
    const int e = tid >> 2, p = tid & 3;
    const int eg = mblk + e;
    float act[6], rst[3];
    #pragma unroll
    for (int i = 0; i < 6; ++i) act[i] = activity[eg * 6 + i];
    #pragma unroll
    for (int i = 0; i < 3; ++i) rst[i] = rest[eg * 3 + i];
    float ha[32];
    for (int j = 0; j < 32; ++j) {
      float s = ab1[j];
      #pragma unroll
      for (int i = 0; i < 6; ++i) s = __builtin_fmaf(act[i], aW1[i * 32 + j], s);
      ha[j] = fmaxf(s, 0.0f);
    }
    float hr[16];
    for (int j = 0; j < 16; ++j) {
      float s = rb1[j];
      #pragma unroll
      for (int i = 0; i < 3; ++i) s = __builtin_fmaf(rst[i], rW1[i * 16 + j], s);
      hr[j] = fmaxf(s, 0.0f);
    }
    for (int oo = 0; oo < 24; ++oo) {
      int o = p * 24 + oo;
      float v;
      if (o < 64) {
        v = ab2[o];
        for (int j = 0; j < 32; ++j) v = __builtin_fmaf(ha[j], aW2[j * 64 + o], v);
      } else {
        int ro = o - 64;
        v = rb2[ro];
        for (int j = 0; j < 16; ++j) v = __builtin_fmaf(hr[j], rW2[j * 32 + ro], v);
      }
      lds.u.ar[e][o] = v;
    }
  }
  // no barrier needed: each wave reads only its own 16 ar rows below.

  // ---------------- c1 context fold: c1[batch n][feat 16t+4q+r] ----------------
  f32x4 c1v[8];
  #pragma unroll
  for (int t = 0; t < 8; ++t)
    c1v[t] = *(const f32x4*)(db1 + t * 16 + quad * 4);
  for (int k = 0; k < 96; ++k) {
    float av = lds.u.ar[slab + n][k];
    #pragma unroll
    for (int t = 0; t < 8; ++t) {
      f32x4 w = *(const f32x4*)(dW1 + (10 + k) * 128 + t * 16 + quad * 4);
      #pragma unroll
      for (int r = 0; r < 4; ++r) c1v[t][r] = __builtin_fmaf(av, w[r], c1v[t][r]);
    }
  }
  __syncthreads();   // ar dead everywhere; wfr (union) may now be written.

  // ---------------- weight A-frags (W^T, pi-permuted k) ----------------
  // pi: slot (quad,j) -> feature fbase + 16*(j>>2) + 4*quad + (j&3)
  #pragma unroll
  for (int t = 0; t < 8; ++t) {            // L1 z-part -> LDS (K=16 real)
    short tmp[8];
    #pragma unroll
    for (int j = 0; j < 8; ++j) {
      float v = 0.0f;
      if (j < 4) {
        int f = 4 * quad + j;
        if (f < 10) v = dW1[f * 128 + t * 16 + n];
        else if (f == 10) v = dW1[106 * 128 + t * 16 + n];
      }
      tmp[j] = f2bf(v);
    }
    *(sh8*)&lds.u.s.wfr[W1F + t][lane][0] =
        (sh8){tmp[0],tmp[1],tmp[2],tmp[3],tmp[4],tmp[5],tmp[6],tmp[7]};
  }
  sh8 w2a[4][4];                           // W2^T t2=0..3 regs, t2=4..7 LDS
  #pragma unroll
  for (int t2 = 0; t2 < 8; ++t2) {
    #pragma unroll
    for (int kt = 0; kt < 4; ++kt) {
      short tmp[8];
      #pragma unroll
      for (int j = 0; j < 8; ++j) {
        int f = 32 * kt + 16 * (j >> 2) + 4 * quad + (j & 3);
        tmp[j] = f2bf(dW2[f * 128 + t2 * 16 + n]);
      }
      sh8 fr = (sh8){tmp[0],tmp[1],tmp[2],tmp[3],tmp[4],tmp[5],tmp[6],tmp[7]};
      if (t2 < 4) w2a[t2][kt] = fr;
      else *(sh8*)&lds.u.s.wfr[W2F + (t2 - 4) * 4 + kt][lane][0] = fr;
    }
  }
  sh8 w3a[4];                              // W3^T regs: rows m>=10 zeroed
  #pragma unroll
  for (int kt = 0; kt < 4; ++kt) {
    short tmp[8];
    #pragma unroll
    for (int j = 0; j < 8; ++j) {
      int f = 32 * kt + 16 * (j >> 2) + 4 * quad + (j & 3);
      tmp[j] = f2bf((n < 10) ? dW3[f * 10 + n] : 0.0f);
    }
    w3a[kt] = (sh8){tmp[0],tmp[1],tmp[2],tmp[3],tmp[4],tmp[5],tmp[6],tmp[7]};
  }
  sh8 g1a[2];                              // G1^T regs, L2E-scaled (softplus fold)
  #pragma unroll
  for (int t = 0; t < 2; ++t) {
    short tmp[8];
    #pragma unroll
    for (int j = 0; j < 8; ++j) {
      float v = 0.0f;
      if (j < 4) {
        int f = 4 * quad + j;
        if (f < 10) v = gW1[f * 32 + t * 16 + n];
        else if (f == 10) v = gW1[10 * 32 + t * 16 + n];
      }
      tmp[j] = f2bf(L2E * v);
    }
    g1a[t] = (sh8){tmp[0],tmp[1],tmp[2],tmp[3],tmp[4],tmp[5],tmp[6],tmp[7]};
  }
  sh8 g2a;                                 // G2^T reg: K=32 (both halves real)
  {
    short tmp[8];
    #pragma unroll
    for (int j = 0; j < 8; ++j) {
      int h = 16 * (j >> 2) + 4 * quad + (j & 3);
      tmp[j] = f2bf((n < 10) ? gW2[h * 10 + n] : 0.0f);
    }
    g2a = (sh8){tmp[0],tmp[1],tmp[2],tmp[3],tmp[4],tmp[5],tmp[6],tmp[7]};
  }

  // ---------------- bias folds (D layout: row = 4q + r) ----------------
  f32x4 c2v[8];                            // db2 as L2 MFMA C-init
  #pragma unroll
  for (int t2 = 0; t2 < 8; ++t2) {
    #pragma unroll
    for (int r = 0; r < 4; ++r)
      c2v[t2][r] = db2[t2 * 16 + quad * 4 + r];
  }
  f32x4 cd3v, cg1v0, cg1v1, cg2v;
  #pragma unroll
  for (int r = 0; r < 4; ++r) {
    int o = quad * 4 + r;
    cd3v[r]  = (o < 10) ? db3[o] : 0.0f;
    cg1v0[r] = L2E * gb1[o];
    cg1v1[r] = L2E * gb1[16 + o];
    cg2v[r]  = (o < 10) ? gb2[o] : 0.0f;
  }

  // ---------------- z init (registers, D layout), out[0] ----------------
  f32x4 zv = {0.0f, 0.0f, 0.0f, 0.0f};
  {
    const float* zp = z0 + (size_t)rowg * 10 + quad * 4;
    float* o0 = out + (size_t)rowg * 10 + quad * 4;
    if (quad < 2) {
      f32x2 a = *(const f32x2*)zp, b = *(const f32x2*)(zp + 2);
      zv[0] = a.x; zv[1] = a.y; zv[2] = b.x; zv[3] = b.y;
      *(f32x2*)o0 = a; *(f32x2*)(o0 + 2) = b;
    } else if (quad == 2) {
      f32x2 a = *(const f32x2*)zp;
      zv[0] = a.x; zv[1] = a.y;
      *(f32x2*)o0 = a;
      zv[2] = tcur;                 // feature 10 = t; feature 11 stays 0
    }
  }
  const float* np = noise + (size_t)rowg * 10 + quad * 4;
  float*       op = out + (size_t)B_TOT * 10 + (size_t)rowg * 10 + quad * 4;

  #pragma unroll 1
  for (int s = 0; s < NSTEP; ++s) {
    // Anti-LICM: keep the LDS frag reads in-loop (R5 lesson).
    asm volatile("" ::: "memory");

    float tnext = lds.tsl[s + 1];
    float dtv   = tnext - tcur;
    float sdt   = __builtin_amdgcn_sqrtf(dtv);

    // noise prefetch (vector, used at step end)
    f32x4 epsv = {0.0f, 0.0f, 0.0f, 0.0f};
    if (quad < 2) {
      f32x2 a = *(const f32x2*)np, b = *(const f32x2*)(np + 2);
      epsv[0] = a.x; epsv[1] = a.y; epsv[2] = b.x; epsv[3] = b.y;
    } else if (quad == 2) {
      f32x2 a = *(const f32x2*)np;
      epsv[0] = a.x; epsv[1] = a.y;
    }
    np += (size_t)B_TOT * 10;

    // W1 frag reads issued early; latency hides under diffusion (reg frags)
    sh8 w1v[8];
    #pragma unroll
    for (int t = 0; t < 8; ++t)
      w1v[t] = *(const sh8*)&lds.u.s.wfr[W1F + t][lane][0];

    // z B-frag (k = 4q + r via pi; upper half zero-weighted)
    sh8 zf = mk4(cvtpk(zv[0], zv[1]), cvtpk(zv[2], zv[3]), 0u, 0u);

    // ---- diffusion: hg = softplus(zt @ G1), accf = hg @ G2 (all-register) ----
    f32x4 accf;
    {
      f32x4 g0 = MFMA(g1a[0], zf, cg1v0);
      f32x4 g1 = MFMA(g1a[1], zf, cg1v1);
      sh8 gb = mk4(cvtpk(softplus_post(g0[0]), softplus_post(g0[1])),
                   cvtpk(softplus_post(g0[2]), softplus_post(g0[3])),
                   cvtpk(softplus_post(g1[0]), softplus_post(g1[1])),
                   cvtpk(softplus_post(g1[2]), softplus_post(g1[3])));
      accf = MFMA(g2a, gb, cg2v);
    }

    // ---- drift L1: h1 = tanh(zt @ W1z + c1), rational tanh ----
    sh8 h1f[4];
    #pragma unroll
    for (int kt = 0; kt < 4; ++kt) {
      f32x4 ae = MFMA(w1v[2 * kt],     zf, c1v[2 * kt]);
      f32x4 ao = MFMA(w1v[2 * kt + 1], zf, c1v[2 * kt + 1]);
      h1f[kt] = mk4(tanh2pk(ae[0], ae[1]), tanh2pk(ae[2], ae[3]),
                    tanh2pk(ao[0], ao[1]), tanh2pk(ao[2], ao[3]));
    }

    // ---- drift L2: h2 = tanh(h1 @ W2 + db2) ----
    sh8 h2f[4];
    {                                      // first half: W2 in registers
      f32x4 a2[4];
      #pragma unroll
      for (int t2 = 0; t2 < 4; ++t2) {
        f32x4 acc = c2v[t2];
        #pragma unroll
        for (int kt = 0; kt < 4; ++kt)
          acc = MFMA(w2a[t2][kt], h1f[kt], acc);
        a2[t2] = acc;
      }
      h2f[0] = mk4(tanh2pk(a2[0][0], a2[0][1]), tanh2pk(a2[0][2], a2[0][3]),
                   tanh2pk(a2[1][0], a2[1][1]), tanh2pk(a2[1][2], a2[1][3]));
      h2f[1] = mk4(tanh2pk(a2[2][0], a2[2][1]), tanh2pk(a2[2][2], a2[2][3]),
                   tanh2pk(a2[3][0], a2[3][1]), tanh2pk(a2[3][2], a2[3][3]));
    }
    {                                      // second half: W2 from LDS
      f32x4 a2[4];
      #pragma unroll
      for (int t2 = 0; t2 < 4; ++t2) {
        f32x4 acc = c2v[t2 + 4];
        #pragma unroll
        for (int kt = 0; kt < 4; ++kt) {
          sh8 wb = *(const sh8*)&lds.u.s.wfr[W2F + t2 * 4 + kt][lane][0];
          acc = MFMA(wb, h1f[kt], acc);
        }
        a2[t2] = acc;
      }
      h2f[2] = mk4(tanh2pk(a2[0][0], a2[0][1]), tanh2pk(a2[0][2], a2[0][3]),
                   tanh2pk(a2[1][0], a2[1][1]), tanh2pk(a2[1][2], a2[1][3]));
      h2f[3] = mk4(tanh2pk(a2[2][0], a2[2][1]), tanh2pk(a2[2][2], a2[2][3]),
                   tanh2pk(a2[3][0], a2[3][1]), tanh2pk(a2[3][2], a2[3][3]));
    }

    // ---- drift L3 (all-register) ----
    f32x4 accd = cd3v;
    #pragma unroll
    for (int kt = 0; kt < 4; ++kt)
      accd = MFMA(w3a[kt], h2f[kt], accd);

    // ---- EM update (packed) + vector store ----
    zv = __builtin_elementwise_fma(accf * sdt, epsv, zv + accd * dtv);
    if (quad < 2) {
      *(f32x2*)op       = (f32x2){zv[0], zv[1]};
      *(f32x2*)(op + 2) = (f32x2){zv[2], zv[3]};
    } else if (quad == 2) {
      *(f32x2*)op       = (f32x2){zv[0], zv[1]};
    }
    op += (size_t)B_TOT * 10;
    zv[2] = (quad == 2) ? tnext : zv[2];   // refresh t feature
    tcur = tnext;
  }
}

extern "C" void kernel_launch(void* const* d_in, const int* in_sizes, int n_in,
                              void* d_out, int out_size, void* d_ws, size_t ws_size,
                              hipStream_t stream) {
  (void)in_sizes; (void)n_in; (void)d_ws; (void)ws_size; (void)out_size;
  const float* z0       = (const float*)d_in[0];
  const float* activity = (const float*)d_in[1];
  const float* rest     = (const float*)d_in[2];
  const float* ts       = (const float*)d_in[3];
  const float* noise    = (const float*)d_in[4];
  const float* aW1 = (const float*)d_in[5];
  const float* ab1 = (const float*)d_in[6];
  const float* aW2 = (const float*)d_in[7];
  const float* ab2 = (const float*)d_in[8];
  const float* rW1 = (const float*)d_in[9];
  const float* rb1 = (const float*)d_in[10];
  const float* rW2 = (const float*)d_in[11];
  const float* rb2 = (const float*)d_in[12];
  const float* dW1 = (const float*)d_in[13];
  const float* db1 = (const float*)d_in[14];
  const float* dW2 = (const float*)d_in[15];
  const float* db2 = (const float*)d_in[16];
  const float* dW3 = (const float*)d_in[17];
  const float* db3 = (const float*)d_in[18];
  const float* gW1 = (const float*)d_in[19];
  const float* gb1 = (const float*)d_in[20];
  const float* gW2 = (const float*)d_in[21];
  const float* gb2 = (const float*)d_in[22];
  float* out = (float*)d_out;

  dim3 grid(B_TOT / MT), block(256);
  sde_kernel<<<grid, block, 0, stream>>>(
      z0, activity, rest, ts, noise,
      aW1, ab1, aW2, ab2, rW1, rb1, rW2, rb2,
      dW1, db1, dW2, db2, dW3, db3,
      gW1, gb1, gW2, gb2, out);
}

// Round 7
// 552.967 us; speedup vs baseline: 1.1253x; 1.1253x over previous
//
#include <hip/hip_runtime.h>
#include <cstdint>
#include <cstddef>

// LatentNeuralSDE: 100 sequential EM steps, B=32768, LAT=10.
// R10: exact R8 structure (exp-tanh, SC-folded weights, cvt_pk packing --
// R9's Pade tanh regressed: more issue slots than exp path) + s_setprio(1)
// around the per-step dependent chain. Waves are independent (no in-loop
// barriers) -> attn-like case where setprio measured +4-7% (m191): keeps
// the wave inside its MFMA->tanh->MFMA critical chain advancing while the
// other wave's latency-tolerant tail (stores, noise loads, ds_reads) fills
// stall holes. W1 + W2 t2=4..7 in frag-linear LDS behind anti-LICM
// clobber; W2 t2=0..3 / W3 / G1 / G2 persistent in registers.

#define B_TOT 32768
#define NSTEP 100
#define MT    64

typedef __attribute__((ext_vector_type(8))) short sh8;
typedef __attribute__((ext_vector_type(4))) float f32x4;
typedef __attribute__((ext_vector_type(2))) float f32x2;
typedef __attribute__((ext_vector_type(4))) unsigned int u32x4;

#define MFMA(a, b, c) __builtin_amdgcn_mfma_f32_16x16x32_bf16((a), (b), (c), 0, 0, 0)

#define SC 2.8853900817779268f   // 2/ln2

// fragment table layout in LDS
#define W1F 0            // 8 frags  (L1 z-part, t=0..7; pre-scaled by SC)
#define W2F 8            // 16 frags (t2=4..7, pre-scaled): W2F + (t2-4)*4 + kt
#define NFR 24

struct __align__(16) Lds {
  union {
    float ar[MT][100];               // encoder outputs (prologue only)
    struct {
      short wfr[NFR][64][8];         // frag-linear weight frags (conflict-free)
    } s;
  } u;                               // 25600 B
  float tsl[104];
};

static __device__ __forceinline__ short f2bf(float v) {  // RTNE (weights, one-time)
  unsigned u = __builtin_bit_cast(unsigned, v);
  u += 0x7fffu + ((u >> 16) & 1u);
  return (short)(u >> 16);
}
// 2 f32 -> packed 2x bf16 (RTNE), one HW instruction (no builtin on gfx950)
static __device__ __forceinline__ unsigned cvtpk(float lo, float hi) {
  unsigned r;
  asm("v_cvt_pk_bf16_f32 %0, %1, %2" : "=v"(r) : "v"(lo), "v"(hi));
  return r;
}
static __device__ __forceinline__ sh8 mk4(unsigned a, unsigned b, unsigned c, unsigned d) {
  return __builtin_bit_cast(sh8, (u32x4){a, b, c, d});
}
// tanh with the 2/ln2 scale pre-folded into the matmul: y = SC*(Wx+b)
static __device__ __forceinline__ float act_post(float y) {
  float e = __builtin_amdgcn_exp2f(y);
  float r = __builtin_amdgcn_rcpf(e + 1.0f);
  return __builtin_fmaf(-2.0f, r, 1.0f);
}
static __device__ __forceinline__ float softplus_fast(float x) {
  float e = __builtin_amdgcn_exp2f(x * 1.4426950408889634f);
  float l = __builtin_amdgcn_logf(e + 1.0f) * 0.6931471805599453f;
  return (x > 20.0f) ? x : l;
}

__global__ __launch_bounds__(256, 2)
void sde_kernel(const float* __restrict__ z0, const float* __restrict__ activity,
                const float* __restrict__ rest, const float* __restrict__ ts,
                const float* __restrict__ noise,
                const float* __restrict__ aW1, const float* __restrict__ ab1,
                const float* __restrict__ aW2, const float* __restrict__ ab2,
                const float* __restrict__ rW1, const float* __restrict__ rb1,
                const float* __restrict__ rW2, const float* __restrict__ rb2,
                const float* __restrict__ dW1, const float* __restrict__ db1,
                const float* __restrict__ dW2, const float* __restrict__ db2,
                const float* __restrict__ dW3, const float* __restrict__ db3,
                const float* __restrict__ gW1, const float* __restrict__ gb1,
                const float* __restrict__ gW2, const float* __restrict__ gb2,
                float* __restrict__ out)
{
  __shared__ Lds lds;
  const int tid  = threadIdx.x;
  const int lane = tid & 63;
  const int wave = tid >> 6;
  const int n    = lane & 15;   // batch col (B/D col) / A-row m in weight gathers
  const int quad = lane >> 4;
  const int slab = wave * 16;
  const int mblk = blockIdx.x * MT;
  const int rowg = mblk + slab + n;   // this lane's global batch row

  if (tid < 101) lds.tsl[tid] = ts[tid];
  float tcur = ts[0];

  // ---------------- encoders -> ar (wave-private rows) ----------------
  {
    const int e = tid >> 2, p = tid & 3;
    const int eg = mblk + e;
    float act[6], rst[3];
    #pragma unroll
    for (int i = 0; i < 6; ++i) act[i] = activity[eg * 6 + i];
    #pragma unroll
    for (int i = 0; i < 3; ++i) rst[i] = rest[eg * 3 + i];
    float ha[32];
    for (int j = 0; j < 32; ++j) {
      float s = ab1[j];
      #pragma unroll
      for (int i = 0; i < 6; ++i) s = __builtin_fmaf(act[i], aW1[i * 32 + j], s);
      ha[j] = fmaxf(s, 0.0f);
    }
    float hr[16];
    for (int j = 0; j < 16; ++j) {
      float s = rb1[j];
      #pragma unroll
      for (int i = 0; i < 3; ++i) s = __builtin_fmaf(rst[i], rW1[i * 16 + j], s);
      hr[j] = fmaxf(s, 0.0f);
    }
    for (int oo = 0; oo < 24; ++oo) {
      int o = p * 24 + oo;
      float v;
      if (o < 64) {
        v = ab2[o];
        for (int j = 0; j < 32; ++j) v = __builtin_fmaf(ha[j], aW2[j * 64 + o], v);
      } else {
        int ro = o - 64;
        v = rb2[ro];
        for (int j = 0; j < 16; ++j) v = __builtin_fmaf(hr[j], rW2[j * 32 + ro], v);
      }
      lds.u.ar[e][o] = v;
    }
  }
  // no barrier needed: each wave reads only its own 16 ar rows below.

  // ---------------- c1 context fold: c1[batch n][feat 16t+4q+r] ----------------
  f32x4 c1v[8];
  #pragma unroll
  for (int t = 0; t < 8; ++t)
    c1v[t] = *(const f32x4*)(db1 + t * 16 + quad * 4);
  for (int k = 0; k < 96; ++k) {
    float av = lds.u.ar[slab + n][k];
    #pragma unroll
    for (int t = 0; t < 8; ++t) {
      f32x4 w = *(const f32x4*)(dW1 + (10 + k) * 128 + t * 16 + quad * 4);
      #pragma unroll
      for (int r = 0; r < 4; ++r) c1v[t][r] = __builtin_fmaf(av, w[r], c1v[t][r]);
    }
  }
  // fold the tanh scale into c1 (matches SC-scaled W1z frags)
  #pragma unroll
  for (int t = 0; t < 8; ++t) {
    #pragma unroll
    for (int r = 0; r < 4; ++r) c1v[t][r] *= SC;
  }
  __syncthreads();   // ar dead everywhere; wfr (union) may now be written.

  // ---------------- weight A-frags (W^T, pi-permuted k) ----------------
  // pi: slot (quad,j) -> feature fbase + 16*(j>>2) + 4*quad + (j&3)
  // LDS frags: all waves write identical data; each wave's own writes are
  // visible to it in-order (no barrier needed).
  #pragma unroll
  for (int t = 0; t < 8; ++t) {            // L1 z-part -> LDS (K=16 real), SC-scaled
    short tmp[8];
    #pragma unroll
    for (int j = 0; j < 8; ++j) {
      float v = 0.0f;
      if (j < 4) {
        int f = 4 * quad + j;
        if (f < 10) v = dW1[f * 128 + t * 16 + n];
        else if (f == 10) v = dW1[106 * 128 + t * 16 + n];
      }
      tmp[j] = f2bf(SC * v);
    }
    *(sh8*)&lds.u.s.wfr[W1F + t][lane][0] =
        (sh8){tmp[0],tmp[1],tmp[2],tmp[3],tmp[4],tmp[5],tmp[6],tmp[7]};
  }
  sh8 w2a[4][4];                           // W2^T t2=0..3 regs, t2=4..7 LDS, SC-scaled
  #pragma unroll
  for (int t2 = 0; t2 < 8; ++t2) {
    #pragma unroll
    for (int kt = 0; kt < 4; ++kt) {
      short tmp[8];
      #pragma unroll
      for (int j = 0; j < 8; ++j) {
        int f = 32 * kt + 16 * (j >> 2) + 4 * quad + (j & 3);
        tmp[j] = f2bf(SC * dW2[f * 128 + t2 * 16 + n]);
      }
      sh8 fr = (sh8){tmp[0],tmp[1],tmp[2],tmp[3],tmp[4],tmp[5],tmp[6],tmp[7]};
      if (t2 < 4) w2a[t2][kt] = fr;
      else *(sh8*)&lds.u.s.wfr[W2F + (t2 - 4) * 4 + kt][lane][0] = fr;
    }
  }
  sh8 w3a[4];                              // W3^T regs: rows m>=10 zeroed (unscaled)
  #pragma unroll
  for (int kt = 0; kt < 4; ++kt) {
    short tmp[8];
    #pragma unroll
    for (int j = 0; j < 8; ++j) {
      int f = 32 * kt + 16 * (j >> 2) + 4 * quad + (j & 3);
      tmp[j] = f2bf((n < 10) ? dW3[f * 10 + n] : 0.0f);
    }
    w3a[kt] = (sh8){tmp[0],tmp[1],tmp[2],tmp[3],tmp[4],tmp[5],tmp[6],tmp[7]};
  }
  sh8 g1a[2];                              // G1^T regs: K=16 real (unscaled)
  #pragma unroll
  for (int t = 0; t < 2; ++t) {
    short tmp[8];
    #pragma unroll
    for (int j = 0; j < 8; ++j) {
      float v = 0.0f;
      if (j < 4) {
        int f = 4 * quad + j;
        if (f < 10) v = gW1[f * 32 + t * 16 + n];
        else if (f == 10) v = gW1[10 * 32 + t * 16 + n];
      }
      tmp[j] = f2bf(v);
    }
    g1a[t] = (sh8){tmp[0],tmp[1],tmp[2],tmp[3],tmp[4],tmp[5],tmp[6],tmp[7]};
  }
  sh8 g2a;                                 // G2^T reg: K=32 (both halves real)
  {
    short tmp[8];
    #pragma unroll
    for (int j = 0; j < 8; ++j) {
      int h = 16 * (j >> 2) + 4 * quad + (j & 3);
      tmp[j] = f2bf((n < 10) ? gW2[h * 10 + n] : 0.0f);
    }
    g2a = (sh8){tmp[0],tmp[1],tmp[2],tmp[3],tmp[4],tmp[5],tmp[6],tmp[7]};
  }

  // ---------------- bias folds (D layout: row = 4q + r) ----------------
  f32x4 c2v[8];                            // SC * db2 as L2 MFMA C-init
  #pragma unroll
  for (int t2 = 0; t2 < 8; ++t2) {
    #pragma unroll
    for (int r = 0; r < 4; ++r)
      c2v[t2][r] = SC * db2[t2 * 16 + quad * 4 + r];
  }
  f32x4 cd3v, cg1v0, cg1v1, cg2v;
  #pragma unroll
  for (int r = 0; r < 4; ++r) {
    int o = quad * 4 + r;
    cd3v[r]  = (o < 10) ? db3[o] : 0.0f;
    cg1v0[r] = gb1[o];
    cg1v1[r] = gb1[16 + o];
    cg2v[r]  = (o < 10) ? gb2[o] : 0.0f;
  }

  // ---------------- z init (registers, D layout), out[0] ----------------
  float zreg[4] = {0.0f, 0.0f, 0.0f, 0.0f};
  {
    const float* zp = z0 + (size_t)rowg * 10 + quad * 4;
    float* o0 = out + (size_t)rowg * 10 + quad * 4;
    if (quad < 2) {
      f32x2 a = *(const f32x2*)zp, b = *(const f32x2*)(zp + 2);
      zreg[0] = a.x; zreg[1] = a.y; zreg[2] = b.x; zreg[3] = b.y;
      *(f32x2*)o0 = a; *(f32x2*)(o0 + 2) = b;
    } else if (quad == 2) {
      f32x2 a = *(const f32x2*)zp;
      zreg[0] = a.x; zreg[1] = a.y;
      *(f32x2*)o0 = a;
      zreg[2] = tcur;               // feature 10 = t; feature 11 stays 0
    }
  }
  const float* np = noise + (size_t)rowg * 10 + quad * 4;
  float*       op = out + (size_t)B_TOT * 10 + (size_t)rowg * 10 + quad * 4;

  #pragma unroll 1
  for (int s = 0; s < NSTEP; ++s) {
    // Anti-LICM: keep the remaining LDS frag reads in-loop (R5 lesson).
    asm volatile("" ::: "memory");

    float tnext = lds.tsl[s + 1];
    float dtv   = tnext - tcur;
    float sdt   = __builtin_amdgcn_sqrtf(dtv);

    // noise prefetch (vector, used at step end)
    float eps0 = 0.0f, eps1 = 0.0f, eps2 = 0.0f, eps3 = 0.0f;
    if (quad < 2) {
      f32x2 a = *(const f32x2*)np, b = *(const f32x2*)(np + 2);
      eps0 = a.x; eps1 = a.y; eps2 = b.x; eps3 = b.y;
    } else if (quad == 2) {
      f32x2 a = *(const f32x2*)np;
      eps0 = a.x; eps1 = a.y;
    }
    np += (size_t)B_TOT * 10;

    // W1 frag reads issued early; latency hides under diffusion (reg frags)
    sh8 w1v[8];
    #pragma unroll
    for (int t = 0; t < 8; ++t)
      w1v[t] = *(const sh8*)&lds.u.s.wfr[W1F + t][lane][0];

    // Raise priority for the latency-critical dependent chain (T5, attn-like
    // independent waves): the co-resident wave's tail fills our stall holes.
    __builtin_amdgcn_s_setprio(1);

    // z B-frag (k = 4q + r via pi; upper half zero-weighted)
    sh8 zf = mk4(cvtpk(zreg[0], zreg[1]), cvtpk(zreg[2], zreg[3]), 0u, 0u);

    // ---- diffusion: hg = softplus(zt @ G1), accf = hg @ G2 (all-register) ----
    f32x4 accf;
    {
      f32x4 g0 = MFMA(g1a[0], zf, cg1v0);
      f32x4 g1 = MFMA(g1a[1], zf, cg1v1);
      sh8 gb = mk4(cvtpk(softplus_fast(g0[0]), softplus_fast(g0[1])),
                   cvtpk(softplus_fast(g0[2]), softplus_fast(g0[3])),
                   cvtpk(softplus_fast(g1[0]), softplus_fast(g1[1])),
                   cvtpk(softplus_fast(g1[2]), softplus_fast(g1[3])));
      accf = MFMA(g2a, gb, cg2v);
    }

    // ---- drift L1: h1 = tanh(zt @ W1z + c1); scale folded into W1z/c1 ----
    sh8 h1f[4];
    #pragma unroll
    for (int kt = 0; kt < 4; ++kt) {
      f32x4 ae = MFMA(w1v[2 * kt],     zf, c1v[2 * kt]);
      f32x4 ao = MFMA(w1v[2 * kt + 1], zf, c1v[2 * kt + 1]);
      h1f[kt] = mk4(cvtpk(act_post(ae[0]), act_post(ae[1])),
                    cvtpk(act_post(ae[2]), act_post(ae[3])),
                    cvtpk(act_post(ao[0]), act_post(ao[1])),
                    cvtpk(act_post(ao[2]), act_post(ao[3])));
    }

    // ---- drift L2: h2 = tanh(h1 @ W2 + db2); scale folded into W2/c2v ----
    sh8 h2f[4];
    {                                      // first half: W2 in registers
      f32x4 a2[4];
      #pragma unroll
      for (int t2 = 0; t2 < 4; ++t2) {
        f32x4 acc = c2v[t2];
        #pragma unroll
        for (int kt = 0; kt < 4; ++kt)
          acc = MFMA(w2a[t2][kt], h1f[kt], acc);
        a2[t2] = acc;
      }
      h2f[0] = mk4(cvtpk(act_post(a2[0][0]), act_post(a2[0][1])),
                   cvtpk(act_post(a2[0][2]), act_post(a2[0][3])),
                   cvtpk(act_post(a2[1][0]), act_post(a2[1][1])),
                   cvtpk(act_post(a2[1][2]), act_post(a2[1][3])));
      h2f[1] = mk4(cvtpk(act_post(a2[2][0]), act_post(a2[2][1])),
                   cvtpk(act_post(a2[2][2]), act_post(a2[2][3])),
                   cvtpk(act_post(a2[3][0]), act_post(a2[3][1])),
                   cvtpk(act_post(a2[3][2]), act_post(a2[3][3])));
    }
    {                                      // second half: W2 from LDS
      f32x4 a2[4];
      #pragma unroll
      for (int t2 = 0; t2 < 4; ++t2) {
        f32x4 acc = c2v[t2 + 4];
        #pragma unroll
        for (int kt = 0; kt < 4; ++kt) {
          sh8 wb = *(const sh8*)&lds.u.s.wfr[W2F + t2 * 4 + kt][lane][0];
          acc = MFMA(wb, h1f[kt], acc);
        }
        a2[t2] = acc;
      }
      h2f[2] = mk4(cvtpk(act_post(a2[0][0]), act_post(a2[0][1])),
                   cvtpk(act_post(a2[0][2]), act_post(a2[0][3])),
                   cvtpk(act_post(a2[1][0]), act_post(a2[1][1])),
                   cvtpk(act_post(a2[1][2]), act_post(a2[1][3])));
      h2f[3] = mk4(cvtpk(act_post(a2[2][0]), act_post(a2[2][1])),
                   cvtpk(act_post(a2[2][2]), act_post(a2[2][3])),
                   cvtpk(act_post(a2[3][0]), act_post(a2[3][1])),
                   cvtpk(act_post(a2[3][2]), act_post(a2[3][3])));
    }

    // ---- drift L3 (all-register) ----
    f32x4 accd = cd3v;
    #pragma unroll
    for (int kt = 0; kt < 4; ++kt)
      accd = MFMA(w3a[kt], h2f[kt], accd);

    __builtin_amdgcn_s_setprio(0);

    // ---- EM update + vector store ----
    {
      float f0 = accf[0] * sdt, f1 = accf[1] * sdt;
      float f2 = accf[2] * sdt, f3 = accf[3] * sdt;
      zreg[0] = __builtin_fmaf(f0, eps0, __builtin_fmaf(accd[0], dtv, zreg[0]));
      zreg[1] = __builtin_fmaf(f1, eps1, __builtin_fmaf(accd[1], dtv, zreg[1]));
      zreg[2] = __builtin_fmaf(f2, eps2, __builtin_fmaf(accd[2], dtv, zreg[2]));
      zreg[3] = __builtin_fmaf(f3, eps3, __builtin_fmaf(accd[3], dtv, zreg[3]));
    }
    if (quad < 2) {
      *(f32x2*)op       = (f32x2){zreg[0], zreg[1]};
      *(f32x2*)(op + 2) = (f32x2){zreg[2], zreg[3]};
    } else if (quad == 2) {
      *(f32x2*)op       = (f32x2){zreg[0], zreg[1]};
    }
    op += (size_t)B_TOT * 10;
    zreg[2] = (quad == 2) ? tnext : zreg[2];   // refresh t feature
    tcur = tnext;
  }
}

extern "C" void kernel_launch(void* const* d_in, const int* in_sizes, int n_in,
                              void* d_out, int out_size, void* d_ws, size_t ws_size,
                              hipStream_t stream) {
  (void)in_sizes; (void)n_in; (void)d_ws; (void)ws_size; (void)out_size;
  const float* z0       = (const float*)d_in[0];
  const float* activity = (const float*)d_in[1];
  const float* rest     = (const float*)d_in[2];
  const float* ts       = (const float*)d_in[3];
  const float* noise    = (const float*)d_in[4];
  const float* aW1 = (const float*)d_in[5];
  const float* ab1 = (const float*)d_in[6];
  const float* aW2 = (const float*)d_in[7];
  const float* ab2 = (const float*)d_in[8];
  const float* rW1 = (const float*)d_in[9];
  const float* rb1 = (const float*)d_in[10];
  const float* rW2 = (const float*)d_in[11];
  const float* rb2 = (const float*)d_in[12];
  const float* dW1 = (const float*)d_in[13];
  const float* db1 = (const float*)d_in[14];
  const float* dW2 = (const float*)d_in[15];
  const float* db2 = (const float*)d_in[16];
  const float* dW3 = (const float*)d_in[17];
  const float* db3 = (const float*)d_in[18];
  const float* gW1 = (const float*)d_in[19];
  const float* gb1 = (const float*)d_in[20];
  const float* gW2 = (const float*)d_in[21];
  const float* gb2 = (const float*)d_in[22];
  float* out = (float*)d_out;

  dim3 grid(B_TOT / MT), block(256);
  sde_kernel<<<grid, block, 0, stream>>>(
      z0, activity, rest, ts, noise,
      aW1, ab1, aW2, ab2, rW1, rb1, rW2, rb2,
      dW1, db1, dW2, db2, dW3, db3,
      gW1, gb1, gW2, gb2, out);
}